// Round 7
// baseline (491.762 us; speedup 1.0000x reference)
//
#include <hip/hip_runtime.h>
#include <math.h>

#define BATCH 8
#define SEQ   2048
#define CDIM  768
#define HDIM  64
#define QROWS 32
#define KVB   32
#define NIT   (SEQ / KVB)   // 64 — multiplicative mask: future region dominates, scan ALL s

typedef float f4 __attribute__((ext_vector_type(4)));
typedef short s8 __attribute__((ext_vector_type(8)));

// swizzled slot (in doubles) for d-pair dp within a 64-double LDS row; grp = row>>2.
// Proven 0-conflict in rounds 2/6.
static __device__ __forceinline__ int swz_off(int dp, int grp) {
    return ((dp + grp) & 31) * 2;
}
// round-to-nearest-even f32 -> bf16 bits
static __device__ __forceinline__ unsigned bf16_rne(float f) {
    unsigned u = __float_as_uint(f);
    return (u + 0x7FFFu + ((u >> 16) & 1u)) >> 16;
}

// exact: mask*scale folded, pow-2 scaling commutes with rounding -> bit-identical
// to (raw * mask) * 0.125 of the reference.
#define MASKC (-99999999999999.0 * 0.125)

// ---------------------------------------------------------------- projection
// q,k fp64 (score ordering must match np); v -> bf16 TRANSPOSED vT[b][d][s]
// (feeds MFMA B-frags as one contiguous b128 read).
__global__ __launch_bounds__(256) void qkv_proj_kernel(
    const float* __restrict__ x,
    const float* __restrict__ Wk,
    const float* __restrict__ Wq,
    const float* __restrict__ Wv,
    double* __restrict__ qd,
    double* __restrict__ kd,
    unsigned short* __restrict__ vtg)
{
    __shared__ float xs[32][68];
    __shared__ float wqs[64 * 64];
    __shared__ float wks[64 * 64];
    __shared__ float wvs[64 * 64];

    const int tid = threadIdx.x;
    const int tx  = tid & 15;
    const int ty  = tid >> 4;
    const size_t row0 = (size_t)blockIdx.x * 32;

    double qa[2][4] = {{0, 0, 0, 0}, {0, 0, 0, 0}};
    double ka[2][4] = {{0, 0, 0, 0}, {0, 0, 0, 0}};
    float  va[2][4] = {{0, 0, 0, 0}, {0, 0, 0, 0}};

    for (int cc = 0; cc < CDIM; cc += 64) {
        __syncthreads();
        #pragma unroll
        for (int it = 0; it < 2; ++it) {
            const int t  = tid + it * 256;
            const int r  = t >> 4;
            const int c4 = t & 15;
            const float4 v4 = *reinterpret_cast<const float4*>(
                &x[(row0 + r) * CDIM + cc + c4 * 4]);
            *reinterpret_cast<float4*>(&xs[r][c4 * 4]) = v4;
        }
        {
            const float4* wqg = reinterpret_cast<const float4*>(&Wq[(size_t)cc * HDIM]);
            const float4* wkg = reinterpret_cast<const float4*>(&Wk[(size_t)cc * HDIM]);
            const float4* wvg = reinterpret_cast<const float4*>(&Wv[(size_t)cc * HDIM]);
            float4* wql = reinterpret_cast<float4*>(wqs);
            float4* wkl = reinterpret_cast<float4*>(wks);
            float4* wvl = reinterpret_cast<float4*>(wvs);
            #pragma unroll
            for (int it = 0; it < 4; ++it) {
                const int t = tid + it * 256;
                wql[t] = wqg[t];
                wkl[t] = wkg[t];
                wvl[t] = wvg[t];
            }
        }
        __syncthreads();
        #pragma unroll 4
        for (int c = 0; c < 64; ++c) {
            const float4 wq4 = *reinterpret_cast<const float4*>(&wqs[c * 64 + tx * 4]);
            const float4 wk4 = *reinterpret_cast<const float4*>(&wks[c * 64 + tx * 4]);
            const float4 wv4 = *reinterpret_cast<const float4*>(&wvs[c * 64 + tx * 4]);
            #pragma unroll
            for (int i = 0; i < 2; ++i) {
                const float  xv = xs[ty * 2 + i][c];
                const double xd = (double)xv;
                qa[i][0] += xd * (double)wq4.x;
                qa[i][1] += xd * (double)wq4.y;
                qa[i][2] += xd * (double)wq4.z;
                qa[i][3] += xd * (double)wq4.w;
                ka[i][0] += xd * (double)wk4.x;
                ka[i][1] += xd * (double)wk4.y;
                ka[i][2] += xd * (double)wk4.z;
                ka[i][3] += xd * (double)wk4.w;
                va[i][0] += xv * wv4.x;
                va[i][1] += xv * wv4.y;
                va[i][2] += xv * wv4.z;
                va[i][3] += xv * wv4.w;
            }
        }
    }
    #pragma unroll
    for (int i = 0; i < 2; ++i) {
        const size_t row = row0 + ty * 2 + i;
        *reinterpret_cast<double2*>(&qd[row * HDIM + tx * 4])     = make_double2(qa[i][0], qa[i][1]);
        *reinterpret_cast<double2*>(&qd[row * HDIM + tx * 4 + 2]) = make_double2(qa[i][2], qa[i][3]);
        *reinterpret_cast<double2*>(&kd[row * HDIM + tx * 4])     = make_double2(ka[i][0], ka[i][1]);
        *reinterpret_cast<double2*>(&kd[row * HDIM + tx * 4 + 2]) = make_double2(ka[i][2], ka[i][3]);
        const int brow = (int)(row >> 11);
        const int trow = (int)(row & (SEQ - 1));
        #pragma unroll
        for (int j = 0; j < 4; ++j)
            vtg[(size_t)brow * (HDIM * SEQ) + (size_t)(4 * tx + j) * SEQ + trow] =
                (unsigned short)bf16_rne(va[i][j]);
    }
}

// ---------------------------------------------------------------- attention
// grid (64, 8): 32 q-rows/block, 256 thr, 4 blocks/CU (40704 B LDS).
// Scores: proven fp64 VALU path (2x2/thread, KVB=32). PV: one bf16 MFMA per
// d-tile; A-frag from bf16 ps, B-frag = single b128 from transposed vT tile.
__global__ __launch_bounds__(256, 4) void attn_kernel(
    const double* __restrict__ qd,
    const double* __restrict__ kd,
    const unsigned short* __restrict__ vtg,
    float* __restrict__ out)
{
    __shared__ __align__(16) double qs[QROWS * 64];          // swizzled [r][d]
    __shared__ __align__(16) double ks[KVB * 64];            // swizzled [s][d]
    __shared__ __align__(16) unsigned short vT[64 * 40];     // [d][s], pad 40 (80 B rows)
    __shared__ __align__(16) unsigned short ps[QROWS * 40];  // [r][s] bf16, pad 40
    __shared__ float sf_row[QROWS];
    __shared__ float l_row[QROWS];

    const int tid  = threadIdx.x;
    const int lane = tid & 63;
    const int w    = tid >> 6;      // wave 0..3
    const int lo   = lane & 15;     // MFMA m/n lane index
    const int hi   = lane >> 4;     // MFMA k-chunk (8 elems)
    const int tx   = tid & 15;      // score cols 2tx,2tx+1
    const int ty   = tid >> 4;      // score rows 2ty,2ty+1
    const int tb   = blockIdx.x;
    const int b    = blockIdx.y;
    const int r0   = tb * QROWS;

    const int c2 = tid & 31;        // staging d-pair
    const int rb = tid >> 5;        // staging row base (0..7)
    const int vd = tid >> 2;        // vT staging: d row (0..63)
    const int vch = tid & 3;        // vT staging: 8-elem s-chunk

    // ---- stage q tile (swizzled, 32 rows)
    {
        const double* qsrc = qd + ((size_t)b * SEQ + r0) * HDIM;
        #pragma unroll
        for (int it = 0; it < 4; ++it) {
            const int r = rb + it * 8;
            const double2 v2 = *reinterpret_cast<const double2*>(
                &qsrc[(size_t)r * HDIM + 2 * c2]);
            *reinterpret_cast<double2*>(&qs[r * 64 + swz_off(c2, r >> 2)]) = v2;
        }
    }

    double m[2];
    float  l[2];
    f4     acc[2];                   // 2 d-tiles, MFMA C layout
    m[0] = m[1] = -1.0e300;
    l[0] = l[1] = 0.f;
    acc[0] = (f4){0.f, 0.f, 0.f, 0.f};
    acc[1] = (f4){0.f, 0.f, 0.f, 0.f};

    // ---- prefetch iter-0 K/V into registers (T14)
    double2 kreg[4];
    uint4   vreg;
    {
        const size_t kvbase = (size_t)b * SEQ * HDIM;
        #pragma unroll
        for (int it = 0; it < 4; ++it)
            kreg[it] = *reinterpret_cast<const double2*>(
                &kd[kvbase + (size_t)(rb + it * 8) * HDIM + 2 * c2]);
        vreg = *reinterpret_cast<const uint4*>(
            &vtg[(size_t)b * (HDIM * SEQ) + (size_t)vd * SEQ + 8 * vch]);
    }
    #pragma unroll
    for (int it = 0; it < 4; ++it) {
        const int r = rb + it * 8;
        *reinterpret_cast<double2*>(&ks[r * 64 + swz_off(c2, r >> 2)]) = kreg[it];
    }
    *reinterpret_cast<uint4*>(&vT[vd * 40 + 8 * vch]) = vreg;
    __syncthreads();                 // B2: staging visible

    const int qg = ty >> 1;          // swizzle group for rows 2ty,2ty+1
    const int mt = w & 1;            // PV m-tile (rows 16mt..)
    const int nh = w >> 1;           // PV d-half (32nh..)

    for (int sb = 0; sb < NIT; ++sb) {
        // ---- issue next tile's global loads (hidden under scores/softmax/PV)
        if (sb + 1 < NIT) {
            const size_t kvbase = ((size_t)b * SEQ + (size_t)(sb + 1) * KVB) * HDIM;
            #pragma unroll
            for (int it = 0; it < 4; ++it)
                kreg[it] = *reinterpret_cast<const double2*>(
                    &kd[kvbase + (size_t)(rb + it * 8) * HDIM + 2 * c2]);
            vreg = *reinterpret_cast<const uint4*>(
                &vtg[(size_t)b * (HDIM * SEQ) + (size_t)vd * SEQ
                     + (size_t)(sb + 1) * KVB + 8 * vch]);
        }

        // ---- scores (fp64 VALU): s[i][j] = q[2ty+i] . k[2tx+j]
        double s00 = 0.0, s01 = 0.0, s10 = 0.0, s11 = 0.0;
        #pragma unroll 4
        for (int dp = 0; dp < 32; ++dp) {
            const int qo = swz_off(dp, qg);
            const int ko = swz_off(dp, tx >> 1);
            const double2 q0 = *reinterpret_cast<const double2*>(&qs[(2 * ty)     * 64 + qo]);
            const double2 q1 = *reinterpret_cast<const double2*>(&qs[(2 * ty + 1) * 64 + qo]);
            const double2 k0 = *reinterpret_cast<const double2*>(&ks[(2 * tx)     * 64 + ko]);
            const double2 k1 = *reinterpret_cast<const double2*>(&ks[(2 * tx + 1) * 64 + ko]);
            s00 += q0.x * k0.x + q0.y * k0.y;
            s01 += q0.x * k1.x + q0.y * k1.y;
            s10 += q1.x * k0.x + q1.y * k0.y;
            s11 += q1.x * k1.x + q1.y * k1.y;
        }

        // ---- faithful mask (folded constant) + online softmax, fp64 logit domain
        const int c0 = sb * KVB + 2 * tx;
        #pragma unroll
        for (int i = 0; i < 2; ++i) {
            const int rloc = 2 * ty + i;
            const int rg   = r0 + rloc;
            const double raw0 = i ? s10 : s00;
            const double raw1 = i ? s11 : s01;
            const double lg0 = raw0 * ((c0     <= rg) ? 0.125 : MASKC);
            const double lg1 = raw1 * ((c0 + 1 <= rg) ? 0.125 : MASKC);
            double tm = fmax(lg0, lg1);
            #pragma unroll
            for (int off = 8; off > 0; off >>= 1)
                tm = fmax(tm, __shfl_xor(tm, off, 16));
            const double mnew = fmax(m[i], tm);
            const double dm   = m[i] - mnew;
            const float  sf   = (dm < -80.0) ? 0.f : expf((float)dm);
            m[i] = mnew;
            l[i] *= sf;
            const double d0 = lg0 - mnew, d1 = lg1 - mnew;
            const float p0 = (d0 < -80.0) ? 0.f : expf((float)d0);
            const float p1 = (d1 < -80.0) ? 0.f : expf((float)d1);
            *reinterpret_cast<unsigned*>(&ps[rloc * 40 + 2 * tx]) =
                bf16_rne(p0) | (bf16_rne(p1) << 16);
            float psum = p0 + p1;
            #pragma unroll
            for (int off = 8; off > 0; off >>= 1)
                psum += __shfl_xor(psum, off, 16);
            l[i] += psum;
            if (tx == 0) sf_row[rloc] = sf;
        }
        __syncthreads();             // B3: ps/sf visible

        // ---- PV: rescale + 2 bf16 MFMA (A: ps row-frag, B: vT col-frag, both b128)
        #pragma unroll
        for (int i = 0; i < 4; ++i) {
            const float sfr = sf_row[16 * mt + 4 * hi + i];
            acc[0][i] *= sfr;
            acc[1][i] *= sfr;
        }
        {
            const s8 af = *reinterpret_cast<const s8*>(&ps[(16 * mt + lo) * 40 + 8 * hi]);
            #pragma unroll
            for (int ntl = 0; ntl < 2; ++ntl) {
                const int d = 16 * (2 * nh + ntl) + lo;
                const s8 bf = *reinterpret_cast<const s8*>(&vT[d * 40 + 8 * hi]);
                acc[ntl] = __builtin_amdgcn_mfma_f32_16x16x32_bf16(af, bf, acc[ntl], 0, 0, 0);
            }
        }
        __syncthreads();             // B1: PV reads done, safe to overwrite ks/vT/ps

        // ---- write next tile's staging from prefetch regs
        if (sb + 1 < NIT) {
            #pragma unroll
            for (int it = 0; it < 4; ++it) {
                const int r = rb + it * 8;
                *reinterpret_cast<double2*>(&ks[r * 64 + swz_off(c2, r >> 2)]) = kreg[it];
            }
            *reinterpret_cast<uint4*>(&vT[vd * 40 + 8 * vch]) = vreg;
            __syncthreads();         // B2: staging visible
        }
    }

    // ---- epilogue
    if (tx == 0) {
        l_row[2 * ty]     = l[0];
        l_row[2 * ty + 1] = l[1];
    }
    __syncthreads();

    #pragma unroll
    for (int ntl = 0; ntl < 2; ++ntl) {
        const int d = 16 * (2 * nh + ntl) + lo;
        #pragma unroll
        for (int i = 0; i < 4; ++i) {
            const int row = 16 * mt + 4 * hi + i;
            out[((size_t)b * SEQ + r0 + row) * HDIM + d] = acc[ntl][i] / l_row[row];
        }
    }
}

extern "C" void kernel_launch(void* const* d_in, const int* in_sizes, int n_in,
                              void* d_out, int out_size, void* d_ws, size_t ws_size,
                              hipStream_t stream)
{
    const float* x  = (const float*)d_in[0];
    const float* Wk = (const float*)d_in[1];
    const float* Wq = (const float*)d_in[2];
    const float* Wv = (const float*)d_in[3];
    float* out = (float*)d_out;

    // workspace: q fp64 (8 MB) | k fp64 (8 MB) | vT bf16 transposed (2 MB)
    double* qd = (double*)d_ws;
    double* kd = qd + (size_t)BATCH * SEQ * HDIM;
    unsigned short* vtg = (unsigned short*)(kd + (size_t)BATCH * SEQ * HDIM);

    qkv_proj_kernel<<<dim3(512), dim3(256), 0, stream>>>(x, Wk, Wq, Wv, qd, kd, vtg);
    attn_kernel<<<dim3(SEQ / QROWS, BATCH), dim3(256), 0, stream>>>(qd, kd, vtg, out);
}